// Round 2
// baseline (465.096 us; speedup 1.0000x reference)
//
#include <hip/hip_runtime.h>

// Problem constants: B=4, N=4096 -> nPoints=16384
#define KN 32                 // neighbors per point
#define FF 64                 // input feature dim
#define CC 256                // H*D channels (H=16 heads, D=16)
#define KV_STRIDE 260         // pad 256->260: all kvS phases <=2-way bank aliased (validated R2)
#define VOFF (KN * KV_STRIDE) // V offset inside kvS (floats)
#define NITER 16              // points per block
#define QSTRIDE 264           // ushorts per qAll row (264*2B = 132 dwords, !=0 mod 32)
#define WSTRIDE 33            // wS stride: head h reads bank (h+k)%32 -> conflict-free

// Faithful-reshape semantics (validated R1/R2):
//   K[b,n,h,k,d] = K_proj[b,n, j=2h+(k>>4), ch=(k&15)*16+d];  V likewise.
//   Q[b,n,h,0,d] = Q_proj[b,n, h*16+d].

typedef __attribute__((ext_vector_type(8)))  short bf16x8;   // 8 bf16 = 4 VGPRs
typedef __attribute__((ext_vector_type(16))) float f32x16;   // 32x32 MFMA acc
typedef __attribute__((ext_vector_type(4)))  float f32x4;    // 16x16 MFMA acc

__device__ inline unsigned short f2bf(float f) {             // fp32->bf16 RNE (epilogue only)
    union { float f; unsigned u; } v; v.f = f;
    unsigned u = v.u + 0x7fffu + ((v.u >> 16) & 1u);
    return (unsigned short)(u >> 16);
}
// HW packed fp32->bf16 RNE: 1 instr per pair vs ~8 for the manual sequence.
__device__ inline unsigned cvt_pk_bf16(float a, float b) {
    unsigned r;
    asm("v_cvt_pk_bf16_f32 %0, %1, %2" : "=v"(r) : "v"(a), "v"(b));
    return r;
}
__device__ inline bf16x8 pack8(float4 a, float4 b) {
    union { bf16x8 v; unsigned u[4]; } r;
    r.u[0] = cvt_pk_bf16(a.x, a.y);  r.u[1] = cvt_pk_bf16(a.z, a.w);
    r.u[2] = cvt_pk_bf16(b.x, b.y);  r.u[3] = cvt_pk_bf16(b.z, b.w);
    return r.v;
}

// LDS producer/consumer barrier WITHOUT the __syncthreads vmcnt(0) drain:
// waits only for outstanding LDS ops, so register-resident global prefetches
// stay in flight across the barrier (m201 8-phase pattern).
__device__ inline void lds_barrier() {
    asm volatile("s_waitcnt lgkmcnt(0)" ::: "memory");
    __builtin_amdgcn_s_barrier();
}

// Single fused kernel. Block = 256 threads (4 waves), NITER points per block.
// Prologue: Q-projection for all 16 points via 16x16x32 MFMA -> qAll (bf16 LDS).
// Main loop is software-pipelined: K/V-projection MFMAs for point i+1 run
// (register-only) concurrently with attention on point i; the LDS writeback
// happens after attention's reads complete. Barriers never drain vmcnt.
__global__ __launch_bounds__(256, 2)
void attn_one(const float* __restrict__ inp,
              const float* __restrict__ query,
              const float* __restrict__ Wq,
              const float* __restrict__ bq,
              const float* __restrict__ Wk,
              const float* __restrict__ bk,
              const float* __restrict__ Wv,
              const float* __restrict__ bv,
              float* __restrict__ out, int nPoints)
{
    __shared__ float kvS[2 * KN * KV_STRIDE];        // 66.5 KB: K then V (fp32)
    __shared__ unsigned short qAllS[NITER * QSTRIDE];// 8.4 KB: pre-scaled Q, bf16
    __shared__ float wS[16 * WSTRIDE];               // softmax weights (intra-wave)

    const int tid  = threadIdx.x;
    const int wave = tid >> 6;
    const int L    = tid & 63;
    const int Lm   = L & 31;       // M/N index inside the 32x32 tile
    const int Lh   = L >> 5;       // k-half selector (32x32x16)
    const int h    = tid >> 4;     // attention head 0..15
    const int d    = tid & 15;     // dim within head
    const int bid  = blockIdx.x;
    const int grid = gridDim.x;

    // ---- stage this block's 16 query rows into kvS scratch (freed later) ----
    float* qIn = kvS;              // 16 rows x 68 floats (pad 64->68)
    {
        const int i  = tid >> 4;           // point slot 0..15
        const int f4 = (tid & 15) * 4;
        const int p  = bid + i * grid;
        if (p < nPoints)
            *(float4*)(qIn + i * 68 + f4) =
                *(const float4*)(query + (size_t)p * FF + f4);
    }

    // ---- prefetch first point's A-row into registers ----
    float4 pf[8];
    {
        const float* arow = inp + (size_t)bid * (KN * FF) + Lm * FF + Lh * 8;
#pragma unroll
        for (int s = 0; s < 4; ++s) {
            pf[2 * s]     = *(const float4*)(arow + s * 16);
            pf[2 * s + 1] = *(const float4*)(arow + s * 16 + 4);
        }
    }

    // ---- Wk/Wv B fragments + bias (validated R2 layout) ----
    // B[k][n]: lane holds k = s*16 + Lh*8 + j, n = chunk*32 + Lm
    bf16x8 Bf[4][4];   // [tile: K0,K1,V0,V1][kstep]
    float  bias[4];
#pragma unroll
    for (int t = 0; t < 4; ++t) {
        const float* W  = (t < 2) ? Wk : Wv;
        const float* bb = (t < 2) ? bk : bv;
        const int ch    = (2 * wave + (t & 1)) * 32 + Lm;
        bias[t] = bb[ch];
#pragma unroll
        for (int s = 0; s < 4; ++s) {
            union { bf16x8 v; unsigned u[4]; } r;
#pragma unroll
            for (int jj = 0; jj < 4; ++jj) {
                const int f = s * 16 + Lh * 8 + 2 * jj;
                r.u[jj] = cvt_pk_bf16(W[(size_t)f * CC + ch], W[(size_t)(f + 1) * CC + ch]);
            }
            Bf[t][s] = r.v;
        }
    }

    // ---- Wq B fragments: 4 N-tiles of 16 per wave, K=64 in 2 steps ----
    // 16x16x32 layouts (HW-verified): A[m=lane&15][k=(lane>>4)*8+j],
    // B[k=(lane>>4)*8+j][n=lane&15], C/D col=lane&15 row=(lane>>4)*4+reg.
    const int nq = L & 15;
    const int kq = (L >> 4) * 8;
    bf16x8 Bq[4][2];
    float  bqv[4];
#pragma unroll
    for (int tt = 0; tt < 4; ++tt) {
        const int ch = wave * 64 + tt * 16 + nq;
        bqv[tt] = bq[ch];
#pragma unroll
        for (int s = 0; s < 2; ++s) {
            union { bf16x8 v; unsigned u[4]; } r;
#pragma unroll
            for (int jj = 0; jj < 4; ++jj) {
                const int f = s * 32 + kq + 2 * jj;
                r.u[jj] = cvt_pk_bf16(Wq[(size_t)f * CC + ch], Wq[(size_t)(f + 1) * CC + ch]);
            }
            Bq[tt][s] = r.v;
        }
    }

    __syncthreads();   // qIn staged

    // ---- Q-projection MFMA: M=16 points, N=256 channels, K=64 ----
    {
        bf16x8 Aq[2];
        const int im = L & 15;
#pragma unroll
        for (int s = 0; s < 2; ++s) {
            const float* qr = qIn + im * 68 + s * 32 + kq;
            Aq[s] = pack8(*(const float4*)qr, *(const float4*)(qr + 4));
        }
#pragma unroll
        for (int tt = 0; tt < 4; ++tt) {
            // bias pre-loaded into the accumulator (C carries it through MFMA)
            f32x4 qa = {bqv[tt], bqv[tt], bqv[tt], bqv[tt]};
#pragma unroll
            for (int s = 0; s < 2; ++s)
                qa = __builtin_amdgcn_mfma_f32_16x16x32_bf16(Aq[s], Bq[tt][s], qa, 0, 0, 0);
            const int ch = wave * 64 + tt * 16 + nq;
#pragma unroll
            for (int r = 0; r < 4; ++r) {
                const int ip = (L >> 4) * 4 + r;    // point slot 0..15
                qAllS[ip * QSTRIDE + ch] = f2bf(qa[r] * 0.25f);
            }
        }
    }
    __syncthreads();   // qAll ready; kvS scratch free

    // ---- pipeline prologue: project K/V of point 0 into kvS ----
    {
        bf16x8 Af[4];
#pragma unroll
        for (int s = 0; s < 4; ++s) Af[s] = pack8(pf[2 * s], pf[2 * s + 1]);

        const int p1 = bid + grid;
        if (p1 < nPoints) {      // issue prefetch for point 1 (in flight below)
            const float* arow = inp + (size_t)p1 * (KN * FF) + Lm * FF + Lh * 8;
#pragma unroll
            for (int s = 0; s < 4; ++s) {
                pf[2 * s]     = *(const float4*)(arow + s * 16);
                pf[2 * s + 1] = *(const float4*)(arow + s * 16 + 4);
            }
        }

        f32x16 acc[4];
#pragma unroll
        for (int t = 0; t < 4; ++t)
#pragma unroll
            for (int r = 0; r < 16; ++r) acc[t][r] = bias[t];
#pragma unroll
        for (int s = 0; s < 4; ++s)
#pragma unroll
            for (int t = 0; t < 4; ++t)
                acc[t] = __builtin_amdgcn_mfma_f32_32x32x16_bf16(Af[s], Bf[t][s], acc[t], 0, 0, 0);

        // C writeback -> kvS.  C: col=chunk*32+Lm, row=(r&3)+8*(r>>2)+4*Lh
#pragma unroll
        for (int t = 0; t < 4; ++t) {
            float* dstbase = kvS + ((t < 2) ? 0 : VOFF);
            const int col  = (2 * wave + (t & 1)) * 32 + Lm;
#pragma unroll
            for (int r = 0; r < 16; ++r) {
                const int jrow = (r & 3) + 8 * (r >> 2) + 4 * Lh;
                dstbase[jrow * KV_STRIDE + col] = acc[t][r];
            }
        }
    }
    lds_barrier();   // kvS(point 0) visible; global prefetch still in flight

    // ================= main loop: attention(i) || MFMA(i+1) =================
    for (int it = 0, p = bid; p < nPoints; ++it, p += grid) {
        const int  pn   = p + grid;
        const bool have = (pn < nPoints);    // block-uniform

        // ---- register-only K/V projection for point i+1 (overlaps attention)
        f32x16 acc[4];
        if (have) {
            bf16x8 Af[4];
#pragma unroll
            for (int s = 0; s < 4; ++s) Af[s] = pack8(pf[2 * s], pf[2 * s + 1]);

            const int pn2 = pn + grid;
            if (pn2 < nPoints) {             // prefetch point i+2
                const float* arow = inp + (size_t)pn2 * (KN * FF) + Lm * FF + Lh * 8;
#pragma unroll
                for (int s = 0; s < 4; ++s) {
                    pf[2 * s]     = *(const float4*)(arow + s * 16);
                    pf[2 * s + 1] = *(const float4*)(arow + s * 16 + 4);
                }
            }
#pragma unroll
            for (int t = 0; t < 4; ++t)
#pragma unroll
                for (int r = 0; r < 16; ++r) acc[t][r] = bias[t];
#pragma unroll
            for (int s = 0; s < 4; ++s)
#pragma unroll
                for (int t = 0; t < 4; ++t)
                    acc[t] = __builtin_amdgcn_mfma_f32_32x32x16_bf16(Af[s], Bf[t][s], acc[t], 0, 0, 0);
        }

        // ---- attention on point i (kvS holds its K/V) ----
        // logits: lane (h,d) owns k = 2d, 2d+1 (same neighbor row)
        const unsigned short* qrow = qAllS + it * QSTRIDE + h * 16;
        const int j0  = 2 * h + (d >> 3);
        const int g16 = ((2 * d) & 15) * 16;
        const float* Krow = kvS + j0 * KV_STRIDE + g16;
        float l0a = 0.f, l0b = 0.f, l1a = 0.f, l1b = 0.f;
#pragma unroll
        for (int i = 0; i < 16; i += 2) {
            const int dpa = (d + i) & 15;                // rotation: banks spread
            const int dpb = (d + i + 1) & 15;
            const float qa = __uint_as_float((unsigned)qrow[dpa] << 16);
            const float qb = __uint_as_float((unsigned)qrow[dpb] << 16);
            l0a = fmaf(qa, Krow[dpa],      l0a);
            l0b = fmaf(qb, Krow[dpb],      l0b);
            l1a = fmaf(qa, Krow[16 + dpa], l1a);
            l1b = fmaf(qb, Krow[16 + dpb], l1b);
        }
        const float l0 = l0a + l0b;
        const float l1 = l1a + l1b;

        // softmax across the head's 16 lanes
        float m = fmaxf(l0, l1);
        m = fmaxf(m, __shfl_xor(m, 1));
        m = fmaxf(m, __shfl_xor(m, 2));
        m = fmaxf(m, __shfl_xor(m, 4));
        m = fmaxf(m, __shfl_xor(m, 8));
        float e0 = __expf(l0 - m), e1 = __expf(l1 - m);
        float s2 = e0 + e1;
        s2 += __shfl_xor(s2, 1);
        s2 += __shfl_xor(s2, 2);
        s2 += __shfl_xor(s2, 4);
        s2 += __shfl_xor(s2, 8);
        const float inv = 1.0f / s2;
        wS[h * WSTRIDE + 2 * d]     = e0 * inv;   // intra-wave producer/consumer
        wS[h * WSTRIDE + 2 * d + 1] = e1 * inv;
        __builtin_amdgcn_wave_barrier();

        // output: out[h*16+d] = sum_k w[k] * V[j(k), (k&15)*16+d]
        const float* Vbase = kvS + VOFF;
        float o0 = 0.f, o1 = 0.f, o2 = 0.f, o3 = 0.f;
#pragma unroll
        for (int k = 0; k < KN; k += 4) {
            const int jk = 2 * h + (k >> 4);   // same for the 4-group (k<16 vs >=16)
            o0 = fmaf(wS[h * WSTRIDE + k],     Vbase[jk * KV_STRIDE + ((k    ) & 15) * 16 + d], o0);
            o1 = fmaf(wS[h * WSTRIDE + k + 1], Vbase[jk * KV_STRIDE + ((k + 1) & 15) * 16 + d], o1);
            o2 = fmaf(wS[h * WSTRIDE + k + 2], Vbase[jk * KV_STRIDE + ((k + 2) & 15) * 16 + d], o2);
            o3 = fmaf(wS[h * WSTRIDE + k + 3], Vbase[jk * KV_STRIDE + ((k + 3) & 15) * 16 + d], o3);
        }
        out[(size_t)p * CC + tid] = (o0 + o1) + (o2 + o3);

        lds_barrier();   // all kvS reads of point i done (no vmcnt drain)

        // ---- writeback point i+1's K/V (acc held in registers meanwhile) ----
        if (have) {
#pragma unroll
            for (int t = 0; t < 4; ++t) {
                float* dstbase = kvS + ((t < 2) ? 0 : VOFF);
                const int col  = (2 * wave + (t & 1)) * 32 + Lm;
#pragma unroll
                for (int r = 0; r < 16; ++r) {
                    const int jrow = (r & 3) + 8 * (r >> 2) + 4 * Lh;
                    dstbase[jrow * KV_STRIDE + col] = acc[t][r];
                }
            }
        }
        lds_barrier();   // kvS(point i+1) visible to all waves
    }
}

extern "C" void kernel_launch(void* const* d_in, const int* in_sizes, int n_in,
                              void* d_out, int out_size, void* d_ws, size_t ws_size,
                              hipStream_t stream) {
    const float* inp   = (const float*)d_in[0];
    const float* query = (const float*)d_in[1];
    const float* Wq    = (const float*)d_in[2];
    const float* bq    = (const float*)d_in[3];
    const float* Wk    = (const float*)d_in[4];
    const float* bk    = (const float*)d_in[5];
    const float* Wv    = (const float*)d_in[6];
    const float* bv    = (const float*)d_in[7];
    float* out = (float*)d_out;

    const int nPoints = in_sizes[0] / (KN * FF);          // B*N = 16384
    const int grid    = (nPoints + NITER - 1) / NITER;    // 1024

    attn_one<<<grid, 256, 0, stream>>>(inp, query, Wq, bq, Wk, bk, Wv, bv,
                                       out, nPoints);
}

// Round 3
// 293.267 us; speedup vs baseline: 1.5859x; 1.5859x over previous
//
#include <hip/hip_runtime.h>

// Problem constants: B=4, N=4096 -> nPoints=16384
#define KN 32                 // neighbors per point
#define FF 64                 // input feature dim
#define CC 256                // H*D channels (H=16 heads, D=16)
#define KV_STRIDE 260         // pad 256->260 (validated R2); K half is chunk-XOR swizzled
#define VOFF (KN * KV_STRIDE) // V offset inside kvS (floats)
#define NITER 16              // points per block
#define QSTRIDE 264           // ushorts per qAll row; 528B/row -> b128-aligned per (it,h)
#define WSTRIDE 36            // wS stride in floats: 16B-aligned rows for b128 reads

// Faithful-reshape semantics (validated R1/R2):
//   K[b,n,h,k,d] = K_proj[b,n, j=2h+(k>>4), ch=(k&15)*16+d];  V likewise.
//   Q[b,n,h,0,d] = Q_proj[b,n, h*16+d].
// K-half of kvS stores channel c at swizzled offset within its row:
//   c = s*32 + 4w + e  (s=c>>5, w=(c>>2)&7, e=c&3)  ->  c' = s*32 + 4*(w^s) + e
// Bijective per row; makes the 8x ds_read_b128 logit reads bank-conflict-free
// while keeping the scalar write side <=2-way (free).

typedef __attribute__((ext_vector_type(8)))  short bf16x8;   // 8 bf16 = 4 VGPRs
typedef __attribute__((ext_vector_type(16))) float f32x16;   // 32x32 MFMA acc
typedef __attribute__((ext_vector_type(4)))  float f32x4;    // 16x16 MFMA acc

__device__ inline unsigned short f2bf(float f) {             // fp32->bf16 RNE (prologue only)
    union { float f; unsigned u; } v; v.f = f;
    unsigned u = v.u + 0x7fffu + ((v.u >> 16) & 1u);
    return (unsigned short)(u >> 16);
}
// HW packed fp32->bf16 RNE: 1 instr per pair.
__device__ inline unsigned cvt_pk_bf16(float a, float b) {
    unsigned r;
    asm("v_cvt_pk_bf16_f32 %0, %1, %2" : "=v"(r) : "v"(a), "v"(b));
    return r;
}
__device__ inline bf16x8 pack8(float4 a, float4 b) {
    union { bf16x8 v; unsigned u[4]; } r;
    r.u[0] = cvt_pk_bf16(a.x, a.y);  r.u[1] = cvt_pk_bf16(a.z, a.w);
    r.u[2] = cvt_pk_bf16(b.x, b.y);  r.u[3] = cvt_pk_bf16(b.z, b.w);
    return r.v;
}

// LDS producer/consumer barrier WITHOUT the __syncthreads vmcnt(0) drain:
// global prefetches (A-row, out-stores) stay in flight across the barrier.
__device__ inline void lds_barrier() {
    asm volatile("s_waitcnt lgkmcnt(0)" ::: "memory");
    __builtin_amdgcn_s_barrier();
}

// Single fused kernel. Block = 256 threads (4 waves), NITER points per block.
// Sequential per-point schedule (R1-validated): MFMA -> writeback -> barrier ->
// attention -> barrier. No MFMA acc lives across attention (R2 spill lesson).
__global__ __launch_bounds__(256, 2)
void attn_one(const float* __restrict__ inp,
              const float* __restrict__ query,
              const float* __restrict__ Wq,
              const float* __restrict__ bq,
              const float* __restrict__ Wk,
              const float* __restrict__ bk,
              const float* __restrict__ Wv,
              const float* __restrict__ bv,
              float* __restrict__ out, int nPoints)
{
    __shared__ float kvS[2 * KN * KV_STRIDE];        // 66.5 KB: K (swizzled) then V
    __shared__ unsigned short qAllS[NITER * QSTRIDE];// 8.4 KB: pre-scaled Q, bf16
    __shared__ float wS[16 * WSTRIDE];               // softmax weights (intra-wave)

    const int tid  = threadIdx.x;
    const int wave = tid >> 6;
    const int L    = tid & 63;
    const int Lm   = L & 31;       // M/N index inside the 32x32 tile
    const int Lh   = L >> 5;       // k-half selector (32x32x16)
    const int h    = tid >> 4;     // attention head 0..15
    const int d    = tid & 15;     // dim within head
    const int bid  = blockIdx.x;
    const int grid = gridDim.x;

    // ---- stage this block's 16 query rows into kvS scratch (freed later) ----
    float* qIn = kvS;              // 16 rows x 68 floats (pad 64->68)
    {
        const int i  = tid >> 4;           // point slot 0..15
        const int f4 = (tid & 15) * 4;
        const int p  = bid + i * grid;
        if (p < nPoints)
            *(float4*)(qIn + i * 68 + f4) =
                *(const float4*)(query + (size_t)p * FF + f4);
    }

    // ---- prefetch first point's A-row into registers ----
    float4 pf[8];
    {
        const float* arow = inp + (size_t)bid * (KN * FF) + Lm * FF + Lh * 8;
#pragma unroll
        for (int s = 0; s < 4; ++s) {
            pf[2 * s]     = *(const float4*)(arow + s * 16);
            pf[2 * s + 1] = *(const float4*)(arow + s * 16 + 4);
        }
    }

    // ---- Wk/Wv B fragments + bias (validated R2 layout) ----
    // B[k][n]: lane holds k = s*16 + Lh*8 + j, n = chunk*32 + Lm
    bf16x8 Bf[4][4];   // [tile: K0,K1,V0,V1][kstep]
    float  bias[4];
#pragma unroll
    for (int t = 0; t < 4; ++t) {
        const float* W  = (t < 2) ? Wk : Wv;
        const float* bb = (t < 2) ? bk : bv;
        const int ch    = (2 * wave + (t & 1)) * 32 + Lm;
        bias[t] = bb[ch];
#pragma unroll
        for (int s = 0; s < 4; ++s) {
            union { bf16x8 v; unsigned u[4]; } r;
#pragma unroll
            for (int jj = 0; jj < 4; ++jj) {
                const int f = s * 16 + Lh * 8 + 2 * jj;
                r.u[jj] = cvt_pk_bf16(W[(size_t)f * CC + ch], W[(size_t)(f + 1) * CC + ch]);
            }
            Bf[t][s] = r.v;
        }
    }

    // ---- Wq B fragments: 4 N-tiles of 16 per wave, K=64 in 2 steps ----
    const int nq = L & 15;
    const int kq = (L >> 4) * 8;
    bf16x8 Bq[4][2];
    float  bqv[4];
#pragma unroll
    for (int tt = 0; tt < 4; ++tt) {
        const int ch = wave * 64 + tt * 16 + nq;
        bqv[tt] = bq[ch];
#pragma unroll
        for (int s = 0; s < 2; ++s) {
            union { bf16x8 v; unsigned u[4]; } r;
#pragma unroll
            for (int jj = 0; jj < 4; ++jj) {
                const int f = s * 32 + kq + 2 * jj;
                r.u[jj] = cvt_pk_bf16(Wq[(size_t)f * CC + ch], Wq[(size_t)(f + 1) * CC + ch]);
            }
            Bq[tt][s] = r.v;
        }
    }

    __syncthreads();   // qIn staged

    // ---- Q-projection MFMA: M=16 points, N=256 channels, K=64 ----
    {
        bf16x8 Aq[2];
        const int im = L & 15;
#pragma unroll
        for (int s = 0; s < 2; ++s) {
            const float* qr = qIn + im * 68 + s * 32 + kq;
            Aq[s] = pack8(*(const float4*)qr, *(const float4*)(qr + 4));
        }
#pragma unroll
        for (int tt = 0; tt < 4; ++tt) {
            f32x4 qa = {bqv[tt], bqv[tt], bqv[tt], bqv[tt]};  // bias via C
#pragma unroll
            for (int s = 0; s < 2; ++s)
                qa = __builtin_amdgcn_mfma_f32_16x16x32_bf16(Aq[s], Bq[tt][s], qa, 0, 0, 0);
            const int ch = wave * 64 + tt * 16 + nq;
#pragma unroll
            for (int r = 0; r < 4; ++r) {
                const int ip = (L >> 4) * 4 + r;    // point slot 0..15
                qAllS[ip * QSTRIDE + ch] = f2bf(qa[r] * 0.25f);
            }
        }
    }
    __syncthreads();   // qAll ready; kvS scratch free

    // per-thread constant indices for the attention phase
    const int sR = d & 7;                  // K segment this lane consumes
    const int j0 = 2 * h + (d >> 3);       // K row for k = 2d, 2d+1

    // ================= main loop over this block's points =================
    for (int it = 0, p = bid; p < nPoints; ++it, p += grid) {
        // pack A fragments from prefetched registers
        bf16x8 Af[4];
#pragma unroll
        for (int s = 0; s < 4; ++s) Af[s] = pack8(pf[2 * s], pf[2 * s + 1]);

        // prefetch next point's A-row (stays in flight across lds_barrier)
        const int pn = p + grid;
        if (pn < nPoints) {
            const float* arow = inp + (size_t)pn * (KN * FF) + Lm * FF + Lh * 8;
#pragma unroll
            for (int s = 0; s < 4; ++s) {
                pf[2 * s]     = *(const float4*)(arow + s * 16);
                pf[2 * s + 1] = *(const float4*)(arow + s * 16 + 4);
            }
        }

        // K/V projection MFMAs — bias pre-loaded into the accumulator
        f32x16 acc[4];
#pragma unroll
        for (int t = 0; t < 4; ++t)
#pragma unroll
            for (int r = 0; r < 16; ++r) acc[t][r] = bias[t];
#pragma unroll
        for (int s = 0; s < 4; ++s)
#pragma unroll
            for (int t = 0; t < 4; ++t)
                acc[t] = __builtin_amdgcn_mfma_f32_32x32x16_bf16(Af[s], Bf[t][s], acc[t], 0, 0, 0);

        // C writeback -> kvS.  C: col=chunk*32+Lm, row=(r&3)+8*(r>>2)+4*Lh
        // K tiles (t<2) use the chunk-XOR swizzled column; V tiles plain.
#pragma unroll
        for (int t = 0; t < 4; ++t) {
            const int s8 = 2 * wave + (t & 1);          // col>>5
            const int col = (t < 2)
                ? s8 * 32 + (((Lm >> 2) ^ s8) << 2) + (Lm & 3)   // swizzled (K)
                : s8 * 32 + Lm;                                   // plain (V)
            float* dstbase = kvS + ((t < 2) ? 0 : VOFF);
#pragma unroll
            for (int r = 0; r < 16; ++r) {
                const int jrow = (r & 3) + 8 * (r >> 2) + 4 * Lh;
                dstbase[jrow * KV_STRIDE + col] = acc[t][r];
            }
        }

        // early q-row load: 2x ds_read_b128 (broadcast across head lanes);
        // completes during the barrier's lgkmcnt(0) drain.
        const unsigned short* qp = qAllS + it * QSTRIDE + h * 16;
        uint4 qA = *(const uint4*)qp;          // Q[h,0..7]  (bf16 pairs)
        uint4 qB = *(const uint4*)(qp + 8);    // Q[h,8..15]

        lds_barrier();   // kvS(point p) visible; global prefetch still in flight

        // ---- logits: lane (h,d) owns k = 2d, 2d+1 (same neighbor row) ----
        // K chunk reads: 8x ds_read_b128, swizzle-matched, conflict-free.
        const float* kb = kvS + j0 * KV_STRIDE + sR * 32;
        float4 ck[8];
#pragma unroll
        for (int w = 0; w < 8; ++w)
            ck[w] = *(const float4*)(kb + (((w ^ sR)) << 2));

        // unpack Q row (bf16 -> f32), statically indexed
        union { uint4 v; unsigned u[4]; } ua, ub;
        ua.v = qA;  ub.v = qB;
        float qv[16];
#pragma unroll
        for (int j = 0; j < 4; ++j) {
            qv[2 * j]     = __uint_as_float(ua.u[j] << 16);
            qv[2 * j + 1] = __uint_as_float(ua.u[j] & 0xffff0000u);
            qv[8 + 2 * j]     = __uint_as_float(ub.u[j] << 16);
            qv[8 + 2 * j + 1] = __uint_as_float(ub.u[j] & 0xffff0000u);
        }

        float l0a = 0.f, l0b = 0.f, l1a = 0.f, l1b = 0.f;
#pragma unroll
        for (int i = 0; i < 16; i += 2) {
            l0a = fmaf(qv[i],     ck[i >> 2][i & 3],             l0a);
            l0b = fmaf(qv[i + 1], ck[(i + 1) >> 2][(i + 1) & 3], l0b);
            l1a = fmaf(qv[i],     ck[4 + (i >> 2)][i & 3],             l1a);
            l1b = fmaf(qv[i + 1], ck[4 + ((i + 1) >> 2)][(i + 1) & 3], l1b);
        }
        const float l0 = l0a + l0b;
        const float l1 = l1a + l1b;

        // ---- softmax across the head's 16 lanes ----
        float m = fmaxf(l0, l1);
        m = fmaxf(m, __shfl_xor(m, 1));
        m = fmaxf(m, __shfl_xor(m, 2));
        m = fmaxf(m, __shfl_xor(m, 4));
        m = fmaxf(m, __shfl_xor(m, 8));
        float e0 = __expf(l0 - m), e1 = __expf(l1 - m);
        float s2 = e0 + e1;
        s2 += __shfl_xor(s2, 1);
        s2 += __shfl_xor(s2, 2);
        s2 += __shfl_xor(s2, 4);
        s2 += __shfl_xor(s2, 8);
        const float inv = 1.0f / s2;
        *(float2*)(wS + h * WSTRIDE + 2 * d) = make_float2(e0 * inv, e1 * inv);
        __builtin_amdgcn_wave_barrier();       // intra-wave producer/consumer

        // ---- output: out[h*16+d] = sum_k w[k] * V[j(k), (k&15)*16+d] ----
        float4 wv[8];
#pragma unroll
        for (int g = 0; g < 8; ++g)
            wv[g] = *(const float4*)(wS + h * WSTRIDE + 4 * g);   // broadcast b128

        const float* Vb = kvS + VOFF;
        float o0 = 0.f, o1 = 0.f, o2 = 0.f, o3 = 0.f;
#pragma unroll
        for (int k = 0; k < KN; k += 4) {
            const int jk = 2 * h + (k >> 4);
            o0 = fmaf(wv[k >> 2][0], Vb[jk * KV_STRIDE + ((k    ) & 15) * 16 + d], o0);
            o1 = fmaf(wv[k >> 2][1], Vb[jk * KV_STRIDE + ((k + 1) & 15) * 16 + d], o1);
            o2 = fmaf(wv[k >> 2][2], Vb[jk * KV_STRIDE + ((k + 2) & 15) * 16 + d], o2);
            o3 = fmaf(wv[k >> 2][3], Vb[jk * KV_STRIDE + ((k + 3) & 15) * 16 + d], o3);
        }
        out[(size_t)p * CC + tid] = (o0 + o1) + (o2 + o3);

        lds_barrier();   // kvS fully consumed before next point overwrites
    }
}

extern "C" void kernel_launch(void* const* d_in, const int* in_sizes, int n_in,
                              void* d_out, int out_size, void* d_ws, size_t ws_size,
                              hipStream_t stream) {
    const float* inp   = (const float*)d_in[0];
    const float* query = (const float*)d_in[1];
    const float* Wq    = (const float*)d_in[2];
    const float* bq    = (const float*)d_in[3];
    const float* Wk    = (const float*)d_in[4];
    const float* bk    = (const float*)d_in[5];
    const float* Wv    = (const float*)d_in[6];
    const float* bv    = (const float*)d_in[7];
    float* out = (float*)d_out;

    const int nPoints = in_sizes[0] / (KN * FF);          // B*N = 16384
    const int grid    = (nPoints + NITER - 1) / NITER;    // 1024

    attn_one<<<grid, 256, 0, stream>>>(inp, query, Wq, bq, Wk, bk, Wv, bv,
                                       out, nPoints);
}

// Round 4
// 254.524 us; speedup vs baseline: 1.8273x; 1.1522x over previous
//
#include <hip/hip_runtime.h>

// Problem constants: B=4, N=4096 -> nPoints=16384
#define KN 32                 // neighbors per point
#define FF 64                 // input feature dim
#define CC 256                // H*D channels (H=16 heads, D=16)
#define KSTR 260              // K row stride (floats): K[j][c], 256+4 pad (quad-rotates reads)
#define VST 36                // Vt row stride (floats): Vt[c][j], 32+4 pad
#define VTOFF (KN * KSTR)     // Vt base inside kvS (floats) = 8320
#define NITER 16              // points per block
#define QSTRIDE 264           // ushorts per qAll row; 528B/row -> b128-aligned per (it,h)
#define WSTRIDE 36            // wS stride in floats: 16B-aligned rows for b128 reads

// Faithful-reshape semantics (validated R1/R2):
//   K[b,n,h,k,d] = K_proj[b,n, j=2h+(k>>4), ch=(k&15)*16+d];  V likewise.
//   Q[b,n,h,0,d] = Q_proj[b,n, h*16+d].
// R4 layout change (operand-swapped MFMA, zero extra loads):
//   K stored row-major K[j][c]   -> produced by mfma(Bf,Af): col=j, rows=c-contig
//   V stored transposed Vt[c][j] -> produced by mfma(Af,Bf): col=c, rows=j-contig
// Both writebacks are 4x ds_write_b128 per tile; logit reads 8x ds_read_b128;
// output reads 16x ds_read_b64 (rows 2h,2h+1 adjacent in Vt).

typedef __attribute__((ext_vector_type(8)))  short bf16x8;   // 8 bf16 = 4 VGPRs
typedef __attribute__((ext_vector_type(16))) float f32x16;   // 32x32 MFMA acc
typedef __attribute__((ext_vector_type(4)))  float f32x4;    // 16x16 MFMA acc

__device__ inline unsigned short f2bf(float f) {             // fp32->bf16 RNE (prologue only)
    union { float f; unsigned u; } v; v.f = f;
    unsigned u = v.u + 0x7fffu + ((v.u >> 16) & 1u);
    return (unsigned short)(u >> 16);
}
// HW packed fp32->bf16 RNE: 1 instr per pair.
__device__ inline unsigned cvt_pk_bf16(float a, float b) {
    unsigned r;
    asm("v_cvt_pk_bf16_f32 %0, %1, %2" : "=v"(r) : "v"(a), "v"(b));
    return r;
}
__device__ inline bf16x8 pack8(float4 a, float4 b) {
    union { bf16x8 v; unsigned u[4]; } r;
    r.u[0] = cvt_pk_bf16(a.x, a.y);  r.u[1] = cvt_pk_bf16(a.z, a.w);
    r.u[2] = cvt_pk_bf16(b.x, b.y);  r.u[3] = cvt_pk_bf16(b.z, b.w);
    return r.v;
}

// LDS producer/consumer barrier WITHOUT the __syncthreads vmcnt(0) drain:
// global prefetches (A-row, out-stores) stay in flight across the barrier.
__device__ inline void lds_barrier() {
    asm volatile("s_waitcnt lgkmcnt(0)" ::: "memory");
    __builtin_amdgcn_s_barrier();
}

__global__ __launch_bounds__(256, 2)
void attn_one(const float* __restrict__ inp,
              const float* __restrict__ query,
              const float* __restrict__ Wq,
              const float* __restrict__ bq,
              const float* __restrict__ Wk,
              const float* __restrict__ bk,
              const float* __restrict__ Wv,
              const float* __restrict__ bv,
              float* __restrict__ out, int nPoints)
{
    __shared__ float kvS[KN * KSTR + CC * VST];      // 70.1 KB: K[j][c] then Vt[c][j]
    __shared__ unsigned short qAllS[NITER * QSTRIDE];// 8.4 KB: pre-scaled Q, bf16
    __shared__ float wS[16 * WSTRIDE];               // 2.3 KB: softmax weights

    const int tid  = threadIdx.x;
    const int wave = tid >> 6;
    const int L    = tid & 63;
    const int Lm   = L & 31;       // M/N index inside the 32x32 tile
    const int Lh   = L >> 5;       // k-half selector (32x32x16)
    const int h    = tid >> 4;     // attention head 0..15
    const int d    = tid & 15;     // dim within head
    const int bid  = blockIdx.x;
    const int grid = gridDim.x;

    // ---- stage this block's 16 query rows into kvS scratch (freed later) ----
    float* qIn = kvS;              // 16 rows x 68 floats (pad 64->68)
    {
        const int i  = tid >> 4;           // point slot 0..15
        const int f4 = (tid & 15) * 4;
        const int p  = bid + i * grid;
        if (p < nPoints)
            *(float4*)(qIn + i * 68 + f4) =
                *(const float4*)(query + (size_t)p * FF + f4);
    }

    // ---- prefetch first point's A-row into registers ----
    float4 pf[8];
    {
        const float* arow = inp + (size_t)bid * (KN * FF) + Lm * FF + Lh * 8;
#pragma unroll
        for (int s = 0; s < 4; ++s) {
            pf[2 * s]     = *(const float4*)(arow + s * 16);
            pf[2 * s + 1] = *(const float4*)(arow + s * 16 + 4);
        }
    }

    // ---- Wk/Wv B fragments (validated R2 layout) ----
    // B[k][n]: lane holds k = s*16 + Lh*8 + j, n = chunk*32 + Lm
    bf16x8 Bf[4][4];   // [tile: K0,K1,V0,V1][kstep]
#pragma unroll
    for (int t = 0; t < 4; ++t) {
        const float* W  = (t < 2) ? Wk : Wv;
        const int ch    = (2 * wave + (t & 1)) * 32 + Lm;
#pragma unroll
        for (int s = 0; s < 4; ++s) {
            union { bf16x8 v; unsigned u[4]; } r;
#pragma unroll
            for (int jj = 0; jj < 4; ++jj) {
                const int f = s * 16 + Lh * 8 + 2 * jj;
                r.u[jj] = cvt_pk_bf16(W[(size_t)f * CC + ch], W[(size_t)(f + 1) * CC + ch]);
            }
            Bf[t][s] = r.v;
        }
    }
    // V-tile bias: acc columns share one channel -> scalar per tile
    float biasV[2];
    biasV[0] = bv[(2 * wave + 0) * 32 + Lm];
    biasV[1] = bv[(2 * wave + 1) * 32 + Lm];
    // K-tile bias: swapped-MFMA rows span channels c = chunk*32 + 8g + 4Lh + e
    float4 bkK[2][4];
#pragma unroll
    for (int t = 0; t < 2; ++t)
#pragma unroll
        for (int g = 0; g < 4; ++g)
            bkK[t][g] = *(const float4*)(bk + (2 * wave + t) * 32 + 8 * g + 4 * Lh);

    // ---- Wq B fragments: 4 N-tiles of 16 per wave, K=64 in 2 steps ----
    const int nq = L & 15;
    const int kq = (L >> 4) * 8;
    bf16x8 Bq[4][2];
    float  bqv[4];
#pragma unroll
    for (int tt = 0; tt < 4; ++tt) {
        const int ch = wave * 64 + tt * 16 + nq;
        bqv[tt] = bq[ch];
#pragma unroll
        for (int s = 0; s < 2; ++s) {
            union { bf16x8 v; unsigned u[4]; } r;
#pragma unroll
            for (int jj = 0; jj < 4; ++jj) {
                const int f = s * 32 + kq + 2 * jj;
                r.u[jj] = cvt_pk_bf16(Wq[(size_t)f * CC + ch], Wq[(size_t)(f + 1) * CC + ch]);
            }
            Bq[tt][s] = r.v;
        }
    }

    __syncthreads();   // qIn staged

    // ---- Q-projection MFMA: M=16 points, N=256 channels, K=64 ----
    {
        bf16x8 Aq[2];
        const int im = L & 15;
#pragma unroll
        for (int s = 0; s < 2; ++s) {
            const float* qr = qIn + im * 68 + s * 32 + kq;
            Aq[s] = pack8(*(const float4*)qr, *(const float4*)(qr + 4));
        }
#pragma unroll
        for (int tt = 0; tt < 4; ++tt) {
            f32x4 qa = {bqv[tt], bqv[tt], bqv[tt], bqv[tt]};  // bias via C
#pragma unroll
            for (int s = 0; s < 2; ++s)
                qa = __builtin_amdgcn_mfma_f32_16x16x32_bf16(Aq[s], Bq[tt][s], qa, 0, 0, 0);
            const int ch = wave * 64 + tt * 16 + nq;
#pragma unroll
            for (int r = 0; r < 4; ++r) {
                const int ip = (L >> 4) * 4 + r;    // point slot 0..15
                qAllS[ip * QSTRIDE + ch] = f2bf(qa[r] * 0.25f);
            }
        }
    }
    __syncthreads();   // qAll ready; kvS scratch free

    // per-thread constant indices for the attention phase
    const int sR = d & 7;                  // K segment this lane consumes
    const int j0 = 2 * h + (d >> 3);       // K row for k = 2d, 2d+1

    // ================= main loop over this block's points =================
    for (int it = 0, p = bid; p < nPoints; ++it, p += grid) {
        // pack A fragments from prefetched registers
        bf16x8 Af[4];
#pragma unroll
        for (int s = 0; s < 4; ++s) Af[s] = pack8(pf[2 * s], pf[2 * s + 1]);

        // prefetch next point's A-row (stays in flight across lds_barrier)
        const int pn = p + grid;
        if (pn < nPoints) {
            const float* arow = inp + (size_t)pn * (KN * FF) + Lm * FF + Lh * 8;
#pragma unroll
            for (int s = 0; s < 4; ++s) {
                pf[2 * s]     = *(const float4*)(arow + s * 16);
                pf[2 * s + 1] = *(const float4*)(arow + s * 16 + 4);
            }
        }

        // K tiles (0,1): operand-SWAPPED mfma -> D = (X*Wk)^T, col=j, rows=c.
        // V tiles (2,3): normal orientation  -> D = X*Wv,     col=c, rows=j.
        f32x16 acc[4];
#pragma unroll
        for (int t = 0; t < 2; ++t)
#pragma unroll
            for (int g = 0; g < 4; ++g)
#pragma unroll
                for (int e = 0; e < 4; ++e) acc[t][4 * g + e] = bkK[t][g][e];
#pragma unroll
        for (int t = 2; t < 4; ++t)
#pragma unroll
            for (int r = 0; r < 16; ++r) acc[t][r] = biasV[t - 2];

#pragma unroll
        for (int s = 0; s < 4; ++s) {
#pragma unroll
            for (int t = 0; t < 2; ++t)
                acc[t] = __builtin_amdgcn_mfma_f32_32x32x16_bf16(Bf[t][s], Af[s], acc[t], 0, 0, 0);
#pragma unroll
            for (int t = 2; t < 4; ++t)
                acc[t] = __builtin_amdgcn_mfma_f32_32x32x16_bf16(Af[s], Bf[t][s], acc[t], 0, 0, 0);
        }

        // K writeback: lane = neighbor j=Lm; 4x b128 of consecutive channels
#pragma unroll
        for (int t = 0; t < 2; ++t) {
            float* kr = kvS + Lm * KSTR + (2 * wave + t) * 32 + 4 * Lh;
#pragma unroll
            for (int g = 0; g < 4; ++g) {
                float4 vw = {acc[t][4 * g], acc[t][4 * g + 1], acc[t][4 * g + 2], acc[t][4 * g + 3]};
                *(float4*)(kr + 8 * g) = vw;
            }
        }
        // V writeback (transposed store): lane = channel c; 4x b128 of consecutive j
#pragma unroll
        for (int t = 2; t < 4; ++t) {
            const int col = (2 * wave + (t & 1)) * 32 + Lm;
            float* vr = kvS + VTOFF + col * VST + 4 * Lh;
#pragma unroll
            for (int g = 0; g < 4; ++g) {
                float4 vw = {acc[t][4 * g], acc[t][4 * g + 1], acc[t][4 * g + 2], acc[t][4 * g + 3]};
                *(float4*)(vr + 8 * g) = vw;
            }
        }

        // early q-row load: 2x ds_read_b128 (broadcast across head lanes)
        const unsigned short* qp = qAllS + it * QSTRIDE + h * 16;
        uint4 qA = *(const uint4*)qp;          // Q[h,0..7]  (bf16 pairs)
        uint4 qB = *(const uint4*)(qp + 8);    // Q[h,8..15]

        lds_barrier();   // kvS(point p) visible; global prefetch still in flight

        // ---- logits: lane (h,d) owns k = 2d, 2d+1 (same neighbor row j0) ----
        // 8x ds_read_b128 from K[j0][32*sR .. +31], natural order, quad-rotated by j0.
        const float* kb = kvS + j0 * KSTR + sR * 32;
        float4 ck[8];
#pragma unroll
        for (int w = 0; w < 8; ++w)
            ck[w] = *(const float4*)(kb + 4 * w);

        // unpack Q row (bf16 -> f32), statically indexed
        union { uint4 v; unsigned u[4]; } ua, ub;
        ua.v = qA;  ub.v = qB;
        float qv[16];
#pragma unroll
        for (int j = 0; j < 4; ++j) {
            qv[2 * j]     = __uint_as_float(ua.u[j] << 16);
            qv[2 * j + 1] = __uint_as_float(ua.u[j] & 0xffff0000u);
            qv[8 + 2 * j]     = __uint_as_float(ub.u[j] << 16);
            qv[8 + 2 * j + 1] = __uint_as_float(ub.u[j] & 0xffff0000u);
        }

        float l0a = 0.f, l0b = 0.f, l1a = 0.f, l1b = 0.f;
#pragma unroll
        for (int i = 0; i < 16; i += 2) {
            l0a = fmaf(qv[i],     ck[i >> 2][i & 3],             l0a);
            l0b = fmaf(qv[i + 1], ck[(i + 1) >> 2][(i + 1) & 3], l0b);
            l1a = fmaf(qv[i],     ck[4 + (i >> 2)][i & 3],             l1a);
            l1b = fmaf(qv[i + 1], ck[4 + ((i + 1) >> 2)][(i + 1) & 3], l1b);
        }
        const float l0 = l0a + l0b;
        const float l1 = l1a + l1b;

        // ---- softmax across the head's 16 lanes ----
        float m = fmaxf(l0, l1);
        m = fmaxf(m, __shfl_xor(m, 1));
        m = fmaxf(m, __shfl_xor(m, 2));
        m = fmaxf(m, __shfl_xor(m, 4));
        m = fmaxf(m, __shfl_xor(m, 8));
        float e0 = __expf(l0 - m), e1 = __expf(l1 - m);
        float s2 = e0 + e1;
        s2 += __shfl_xor(s2, 1);
        s2 += __shfl_xor(s2, 2);
        s2 += __shfl_xor(s2, 4);
        s2 += __shfl_xor(s2, 8);
        const float inv = 1.0f / s2;
        *(float2*)(wS + h * WSTRIDE + 2 * d) = make_float2(e0 * inv, e1 * inv);
        __builtin_amdgcn_wave_barrier();       // intra-wave producer/consumer

        // ---- output: out[h*16+d] = sum_k w[k] * V[j(k), (k&15)*16+d] ----
        float4 wv[8];
#pragma unroll
        for (int g = 0; g < 8; ++g)
            wv[g] = *(const float4*)(wS + h * WSTRIDE + 4 * g);   // broadcast b128

        // Vt[c][j]: pair (k=m, k=m+16) shares col c=16m+d, rows 2h / 2h+1 -> b64
        const float* Vb = kvS + VTOFF + d * VST + 2 * h;
        float o0 = 0.f, o1 = 0.f, o2 = 0.f, o3 = 0.f;
#pragma unroll
        for (int mI = 0; mI < 16; mI += 2) {
            const float2 va = *(const float2*)(Vb + (size_t)(16 * mI) * VST);
            const float2 vb = *(const float2*)(Vb + (size_t)(16 * (mI + 1)) * VST);
            o0 = fmaf(wv[mI >> 2][mI & 3],             va.x, o0);
            o1 = fmaf(wv[4 + (mI >> 2)][mI & 3],       va.y, o1);
            o2 = fmaf(wv[(mI + 1) >> 2][(mI + 1) & 3],       vb.x, o2);
            o3 = fmaf(wv[4 + ((mI + 1) >> 2)][(mI + 1) & 3], vb.y, o3);
        }
        out[(size_t)p * CC + tid] = (o0 + o1) + (o2 + o3);

        lds_barrier();   // kvS fully consumed before next point overwrites
    }
}

extern "C" void kernel_launch(void* const* d_in, const int* in_sizes, int n_in,
                              void* d_out, int out_size, void* d_ws, size_t ws_size,
                              hipStream_t stream) {
    const float* inp   = (const float*)d_in[0];
    const float* query = (const float*)d_in[1];
    const float* Wq    = (const float*)d_in[2];
    const float* bq    = (const float*)d_in[3];
    const float* Wk    = (const float*)d_in[4];
    const float* bk    = (const float*)d_in[5];
    const float* Wv    = (const float*)d_in[6];
    const float* bv    = (const float*)d_in[7];
    float* out = (float*)d_out;

    const int nPoints = in_sizes[0] / (KN * FF);          // B*N = 16384
    const int grid    = (nPoints + NITER - 1) / NITER;    // 1024

    attn_one<<<grid, 256, 0, stream>>>(inp, query, Wq, bq, Wk, bk, Wv, bv,
                                       out, nPoints);
}